// Round 7
// baseline (711.287 us; speedup 1.0000x reference)
//
#include <hip/hip_runtime.h>
#include <hip/hip_bf16.h>

// GCN 3-layer: x(N,12) -> 64 -> 128 -> 96, symmetric normalization + self loops.
// N=100000, E=1600000.
//
// R2: CSR + pull-gather (7028 -> 1364 us).
// R3: register-tiled 4x4-microtile transform (1364 -> 693 us).
// R4: associativity reorder (aggregate at 12/64/96) + prescaled rows (693 -> 550).
// R5: two-phase bucketed CSR scatter (550 -> 471).
// R6: (a) fully bucketed CSR build — per-node deg/scan computed in LDS per
//     bucket; removes 1.6M random global atomics (hist) + 100k 3-kernel scan.
//     (b) nontemporal stores on gather outputs (keep L2 for the random reads).
//     (c) degree-sorted node order for F=64/96 gathers (wave-uniform degree).
// R7: fix nontemporal builtin — needs native ext_vector_type, not float4.

static inline int cdiv(int a, int b) { return (a + b - 1) / b; }
constexpr int BLOCK = 256;
constexpr int BSHIFT = 9;                  // 512 nodes per bucket
constexpr int BNODES = 1 << BSHIFT;

typedef float nfloat4 __attribute__((ext_vector_type(4)));

// ---------------- small utils ----------------

__global__ void zero_int_kernel(int* __restrict__ p, int n) {
    int i = blockIdx.x * blockDim.x + threadIdx.x;
    if (i < n) p[i] = 0;
}

__device__ __forceinline__ void nt_store4(float* p, float4 v) {
    nfloat4 nv;
    nv.x = v.x; nv.y = v.y; nv.z = v.z; nv.w = v.w;
    __builtin_nontemporal_store(nv, (nfloat4*)p);
}

// ---------------- CSR build (fully bucketed) ----------------

// per-bucket edge counts (196 buckets), LDS-hist per chunk then global add
template <int CHUNK>
__global__ void bucket_count_kernel(const int* __restrict__ dst, int E,
                                    int* __restrict__ bcnt, int NB) {
    __shared__ int cnt[256];
    for (int i = threadIdx.x; i < NB; i += blockDim.x) cnt[i] = 0;
    __syncthreads();
    const int e0 = blockIdx.x * CHUNK;
    const int e1 = min(e0 + CHUNK, E);
    for (int e = e0 + threadIdx.x; e < e1; e += blockDim.x)
        atomicAdd(&cnt[dst[e] >> BSHIFT], 1);
    __syncthreads();
    for (int i = threadIdx.x; i < NB; i += blockDim.x)
        if (cnt[i]) atomicAdd(&bcnt[i], cnt[i]);
}

// exclusive scan of bcnt (NB<=256) -> gbase; copy to gcur (bin reservations)
__global__ void bucket_scan_kernel(const int* __restrict__ bcnt, int* __restrict__ gbase,
                                   int* __restrict__ gcur, int NB) {
    __shared__ int tmp[256];
    int t = threadIdx.x;
    int v = (t < NB) ? bcnt[t] : 0;
    tmp[t] = v;
    __syncthreads();
    for (int off = 1; off < 256; off <<= 1) {
        int add = (t >= off) ? tmp[t - off] : 0;
        __syncthreads();
        tmp[t] += add;
        __syncthreads();
    }
    if (t < NB) { int ex = tmp[t] - v; gbase[t] = ex; gcur[t] = ex; }
}

// Phase A: bin (s,d) pairs by dst bucket with contiguous-run writes
template <int CHUNK>
__global__ void bin_edges_kernel(const int* __restrict__ ei, int E,
                                 int* __restrict__ gcur, int2* __restrict__ binned,
                                 int NB) {
    __shared__ int cnt[256], base[256], rk[256];
    for (int i = threadIdx.x; i < NB; i += blockDim.x) { cnt[i] = 0; rk[i] = 0; }
    __syncthreads();
    const int e0 = blockIdx.x * CHUNK;
    const int e1 = min(e0 + CHUNK, E);
    for (int e = e0 + threadIdx.x; e < e1; e += blockDim.x)
        atomicAdd(&cnt[ei[E + e] >> BSHIFT], 1);
    __syncthreads();
    for (int i = threadIdx.x; i < NB; i += blockDim.x)
        base[i] = atomicAdd(&gcur[i], cnt[i]);
    __syncthreads();
    for (int e = e0 + threadIdx.x; e < e1; e += blockDim.x) {
        int s = ei[e], d = ei[E + e];
        int b = d >> BSHIFT;
        int r = atomicAdd(&rk[b], 1);
        binned[base[b] + r] = make_int2(s, d);
    }
}

// Phase B: one block per bucket. LDS-hist node degrees, LDS-scan to row_ptr,
// write deg/dinv/row_ptr coalesced, scatter csr_src in the L2-local window.
__global__ void csr_fill_kernel(const int* __restrict__ gbase, const int* __restrict__ bcnt,
                                const int2* __restrict__ binned,
                                int* __restrict__ deg, float* __restrict__ dinv,
                                int* __restrict__ row_ptr, int* __restrict__ csr_src, int N) {
    __shared__ int c[BNODES];    // counts, then cursors
    __shared__ int ps[256];      // pair sums for scan
    const int t = threadIdx.x;
    const int b = blockIdx.x;
    const int node0 = b << BSHIFT;
    c[t] = 0; c[t + 256] = 0;
    __syncthreads();
    const int base = gbase[b];
    const int end = base + bcnt[b];
    for (int e = base + t; e < end; e += 256)
        atomicAdd(&c[binned[e].y - node0], 1);
    __syncthreads();
    const int s0 = c[2 * t], s1 = c[2 * t + 1];
    const int pv = s0 + s1;
    ps[t] = pv;
    __syncthreads();
    for (int off = 1; off < 256; off <<= 1) {
        int add = (t >= off) ? ps[t - off] : 0;
        __syncthreads();
        ps[t] += add;
        __syncthreads();
    }
    const int ex = ps[t] - pv;          // exclusive pair offset within bucket
    const int p0 = base + ex;
    const int p1 = p0 + s0;
    const int n0 = node0 + 2 * t;
    if (n0 < N) {
        row_ptr[n0] = p0; deg[n0] = s0; dinv[n0] = rsqrtf((float)s0 + 1.0f);
        if (n0 + 1 < N) {
            row_ptr[n0 + 1] = p1; deg[n0 + 1] = s1; dinv[n0 + 1] = rsqrtf((float)s1 + 1.0f);
        }
    }
    c[2 * t] = p0; c[2 * t + 1] = p1;   // cursors
    __syncthreads();
    for (int e = base + t; e < end; e += 256) {
        int2 sd = binned[e];
        int pos = atomicAdd(&c[sd.y - node0], 1);
        csr_src[pos] = sd.x;
    }
}

// ---------------- degree counting sort (64 bins) ----------------

__global__ void dhist_kernel(const int* __restrict__ deg, int* __restrict__ dh, int N) {
    __shared__ int cnt[64];
    if (threadIdx.x < 64) cnt[threadIdx.x] = 0;
    __syncthreads();
    int i = blockIdx.x * blockDim.x + threadIdx.x;
    if (i < N) atomicAdd(&cnt[min(deg[i], 63)], 1);
    __syncthreads();
    if (threadIdx.x < 64 && cnt[threadIdx.x]) atomicAdd(&dh[threadIdx.x], cnt[threadIdx.x]);
}

// in-place: dh -> exclusive scan (becomes scatter cursors)
__global__ void dscan_kernel(int* __restrict__ dh) {
    __shared__ int tmp[64];
    int t = threadIdx.x;
    int v = dh[t];
    tmp[t] = v;
    __syncthreads();
    for (int off = 1; off < 64; off <<= 1) {
        int add = (t >= off) ? tmp[t - off] : 0;
        __syncthreads();
        tmp[t] += add;
        __syncthreads();
    }
    dh[t] = tmp[t] - v;
}

__global__ void dperm_kernel(const int* __restrict__ deg, int* __restrict__ dh,
                             int* __restrict__ perm, int N) {
    int i = blockIdx.x * blockDim.x + threadIdx.x;
    if (i >= N) return;
    int pos = atomicAdd(&dh[min(deg[i], 63)], 1);
    perm[pos] = i;
}

// ---------------- prescale ----------------

// xs[i,:] = x[i,:] * dinv[i]   (F=12: 3 float4 chunks per row)
__global__ void prescale_kernel(const float* __restrict__ x, const float* __restrict__ dinv,
                                float* __restrict__ xs, int N) {
    int t = blockIdx.x * blockDim.x + threadIdx.x;
    if (t >= N * 3) return;
    int i = t / 3;
    float di = dinv[i];
    float4 v = ((const float4*)x)[t];
    v.x *= di; v.y *= di; v.z *= di; v.w *= di;
    ((float4*)xs)[t] = v;
}

// ---------------- dense transform (register-tiled) ----------------

__device__ __forceinline__ void fma4(float4& acc, float s, const float4& w) {
    acc.x = fmaf(s, w.x, acc.x);
    acc.y = fmaf(s, w.y, acc.y);
    acc.z = fmaf(s, w.z, acc.z);
    acc.w = fmaf(s, w.w, acc.w);
}

template <int IN, int OUT, bool HAS_BIAS, bool RELU, bool SCALE>
__global__ void transform_kernel(const float* __restrict__ h, const float* __restrict__ W,
                                 const float* __restrict__ bias, const float* __restrict__ dinv,
                                 float* __restrict__ out, int N) {
    constexpr int CG = OUT / 4;        // col groups
    constexpr int THREADS = 8 * CG;    // 8 row groups of 4 rows
    __shared__ float Ws[IN * OUT];
    for (int i = threadIdx.x; i < IN * OUT / 4; i += THREADS)
        ((float4*)Ws)[i] = ((const float4*)W)[i];
    __syncthreads();

    const int c0 = (threadIdx.x % CG) * 4;
    const int r0 = blockIdx.x * 32 + (threadIdx.x / CG) * 4;
    if (r0 >= N) return;  // N % 32 == 0

    const float* __restrict__ hr = h + (size_t)r0 * IN;
    float4 acc[4];
#pragma unroll
    for (int i = 0; i < 4; ++i) acc[i] = make_float4(0.f, 0.f, 0.f, 0.f);

#pragma unroll
    for (int k = 0; k < IN; k += 4) {
        float4 a[4];
#pragma unroll
        for (int i = 0; i < 4; ++i) a[i] = *(const float4*)(hr + (size_t)i * IN + k);
        const float4 w0 = *(const float4*)(Ws + (k + 0) * OUT + c0);
        const float4 w1 = *(const float4*)(Ws + (k + 1) * OUT + c0);
        const float4 w2 = *(const float4*)(Ws + (k + 2) * OUT + c0);
        const float4 w3 = *(const float4*)(Ws + (k + 3) * OUT + c0);
#pragma unroll
        for (int i = 0; i < 4; ++i) {
            fma4(acc[i], a[i].x, w0);
            fma4(acc[i], a[i].y, w1);
            fma4(acc[i], a[i].z, w2);
            fma4(acc[i], a[i].w, w3);
        }
    }

    float4 bb = make_float4(0.f, 0.f, 0.f, 0.f);
    if (HAS_BIAS) bb = *(const float4*)(bias + c0);
#pragma unroll
    for (int i = 0; i < 4; ++i) {
        float4 r = acc[i];
        if (HAS_BIAS) { r.x += bb.x; r.y += bb.y; r.z += bb.z; r.w += bb.w; }
        if (RELU) {
            r.x = fmaxf(r.x, 0.f); r.y = fmaxf(r.y, 0.f);
            r.z = fmaxf(r.z, 0.f); r.w = fmaxf(r.w, 0.f);
        }
        if (SCALE) {
            float di = dinv[r0 + i];
            r.x *= di; r.y *= di; r.z *= di; r.w *= di;
        }
        *(float4*)(out + (size_t)(r0 + i) * OUT + c0) = r;
    }
}

// ---------------- pull gather ----------------

__device__ __forceinline__ void add4(float4& a, const float4& v) {
    a.x += v.x; a.y += v.y; a.z += v.z; a.w += v.w;
}

// hws rows pre-scaled by dinv[src].
// out[i, f0:f0+4] = dinv[i]*(hws[i] + sum_s hws[s]) (+ b)
// PERM: process nodes in degree-sorted order (wave-uniform loop counts).
template <int F, bool HAS_BIAS, bool PERM, bool NT>
__global__ void gather_kernel(const int* __restrict__ row_ptr, const int* __restrict__ deg,
                              const int* __restrict__ csr_src, const int* __restrict__ perm,
                              const float* __restrict__ dinv, const float* __restrict__ hws,
                              const float* __restrict__ b, float* __restrict__ out, int N) {
    constexpr int TPN = F / 4;  // threads per node
    int t = blockIdx.x * blockDim.x + threadIdx.x;
    if (t >= N * TPN) return;
    int slot = t / TPN;
    int c = t - slot * TPN;
    int i = PERM ? perm[slot] : slot;
    int f0 = c * 4;

    const int* __restrict__ sp = csr_src + row_ptr[i];
    int n = deg[i];
    float4 acc = *(const float4*)(hws + (size_t)i * F + f0);  // self loop

    int k = 0;
    for (; k + 8 <= n; k += 8) {
        int s[8];
#pragma unroll
        for (int j = 0; j < 8; ++j) s[j] = sp[k + j];
        float4 v[8];
#pragma unroll
        for (int j = 0; j < 8; ++j) v[j] = *(const float4*)(hws + (size_t)s[j] * F + f0);
#pragma unroll
        for (int j = 0; j < 8; ++j) add4(acc, v[j]);
    }
    for (; k + 4 <= n; k += 4) {
        int s0 = sp[k + 0], s1 = sp[k + 1], s2 = sp[k + 2], s3 = sp[k + 3];
        const float4 v0 = *(const float4*)(hws + (size_t)s0 * F + f0);
        const float4 v1 = *(const float4*)(hws + (size_t)s1 * F + f0);
        const float4 v2 = *(const float4*)(hws + (size_t)s2 * F + f0);
        const float4 v3 = *(const float4*)(hws + (size_t)s3 * F + f0);
        add4(acc, v0); add4(acc, v1); add4(acc, v2); add4(acc, v3);
    }
    for (; k < n; ++k) {
        const float4 v = *(const float4*)(hws + (size_t)sp[k] * F + f0);
        add4(acc, v);
    }

    float di = dinv[i];
    float4 r;
    if (HAS_BIAS) {
        const float4 bb = *(const float4*)(b + f0);
        r.x = fmaf(acc.x, di, bb.x);
        r.y = fmaf(acc.y, di, bb.y);
        r.z = fmaf(acc.z, di, bb.z);
        r.w = fmaf(acc.w, di, bb.w);
    } else {
        r.x = acc.x * di; r.y = acc.y * di; r.z = acc.z * di; r.w = acc.w * di;
    }
    float* op = out + (size_t)i * F + f0;
    if (NT) nt_store4(op, r);
    else *(float4*)op = r;
}

// ---------------- launch ----------------

extern "C" void kernel_launch(void* const* d_in, const int* in_sizes, int n_in,
                              void* d_out, int out_size, void* d_ws, size_t ws_size,
                              hipStream_t stream) {
    const float* x  = (const float*)d_in[0];
    const int*   ei = (const int*)d_in[1];  // (2,E): row0=src, row1=dst
    const float* W1 = (const float*)d_in[2];
    const float* b1 = (const float*)d_in[3];
    const float* W2 = (const float*)d_in[4];
    const float* b2 = (const float*)d_in[5];
    const float* W3 = (const float*)d_in[6];
    const float* b3 = (const float*)d_in[7];
    float* out = (float*)d_out;

    const int N = in_sizes[0] / 12;
    const int E = in_sizes[1] / 2;
    const int NB = cdiv(N, BNODES);  // 196 dst buckets (<=256)

    // workspace layout
    char* ws = (char*)d_ws;
    int*   deg     = (int*)ws;    ws += (size_t)N * sizeof(int);
    int*   row_ptr = (int*)ws;    ws += (size_t)N * sizeof(int);
    int*   perm    = (int*)ws;    ws += (size_t)N * sizeof(int);
    int*   bcnt    = (int*)ws;    ws += 256 * sizeof(int);
    int*   dh      = (int*)ws;    ws += 64 * sizeof(int);
    int*   gbase   = (int*)ws;    ws += 256 * sizeof(int);
    int*   gcur    = (int*)ws;    ws += 256 * sizeof(int);
    float* dinv    = (float*)ws;  ws += (size_t)N * sizeof(float);
    int*   csr_src = (int*)ws;    ws += (size_t)E * sizeof(int);
    float* bufA    = (float*)ws;  ws += (size_t)N * 128 * sizeof(float);  // xs / h1s / h2
    float* bufB    = (float*)ws;                                          // aggx / agg1 / hw3s
    int2*  binned  = (int2*)bufB;  // aliased: consumed by csr_fill before gathers touch bufB

    // ---- CSR build (fully bucketed; no global per-node hist/scan) ----
    zero_int_kernel<<<2, 256, 0, stream>>>(bcnt, 256 + 64);  // bcnt + dh (contiguous)
    bucket_count_kernel<4096><<<cdiv(E, 4096), BLOCK, 0, stream>>>(ei + E, E, bcnt, NB);
    bucket_scan_kernel<<<1, 256, 0, stream>>>(bcnt, gbase, gcur, NB);
    bin_edges_kernel<4096><<<cdiv(E, 4096), BLOCK, 0, stream>>>(ei, E, gcur, binned, NB);
    csr_fill_kernel<<<NB, 256, 0, stream>>>(gbase, bcnt, binned, deg, dinv, row_ptr, csr_src, N);

    // ---- degree counting sort (wave-uniform gather loops) ----
    dhist_kernel<<<cdiv(N, BLOCK), BLOCK, 0, stream>>>(deg, dh, N);
    dscan_kernel<<<1, 64, 0, stream>>>(dh);
    dperm_kernel<<<cdiv(N, BLOCK), BLOCK, 0, stream>>>(deg, dh, perm, N);

    const int tb = cdiv(N, 32);  // transform blocks

    // ---- layer 1: aggregate at F=12, then 12->64 (+b1, relu, *dinv) ----
    prescale_kernel<<<cdiv(N * 3, BLOCK), BLOCK, 0, stream>>>(x, dinv, bufA, N);
    gather_kernel<12, false, false, false><<<cdiv(N * 3, BLOCK), BLOCK, 0, stream>>>(
        row_ptr, deg, csr_src, nullptr, dinv, bufA, nullptr, bufB, N);
    transform_kernel<12, 64, true, true, true><<<tb, 8 * (64 / 4), 0, stream>>>(
        bufB, W1, b1, dinv, bufA, N);  // bufA = h1s (scaled)

    // ---- layer 2: aggregate at F=64, then 64->128 (+b2, relu) ----
    gather_kernel<64, false, true, true><<<cdiv(N * 16, BLOCK), BLOCK, 0, stream>>>(
        row_ptr, deg, csr_src, perm, dinv, bufA, nullptr, bufB, N);
    transform_kernel<64, 128, true, true, false><<<tb, 8 * (128 / 4), 0, stream>>>(
        bufB, W2, b2, dinv, bufA, N);  // bufA = h2

    // ---- layer 3: 128->96 (*dinv), then aggregate at F=96 (+b3) -> out ----
    transform_kernel<128, 96, false, false, true><<<tb, 8 * (96 / 4), 0, stream>>>(
        bufA, W3, nullptr, dinv, bufB, N);  // bufB = hw3s (scaled)
    gather_kernel<96, true, true, true><<<cdiv(N * 24, BLOCK), BLOCK, 0, stream>>>(
        row_ptr, deg, csr_src, perm, dinv, bufB, b3, out, N);
}

// Round 8
// 444.075 us; speedup vs baseline: 1.6017x; 1.6017x over previous
//
#include <hip/hip_runtime.h>
#include <hip/hip_bf16.h>

// GCN 3-layer: x(N,12) -> 64 -> 128 -> 96, symmetric normalization + self loops.
// N=100000, E=1600000.
//
// R2: CSR + pull-gather (7028 -> 1364 us).
// R3: register-tiled 4x4-microtile transform (1364 -> 693 us).
// R4: associativity reorder (aggregate at 12/64/96) + prescaled rows (693 -> 550).
// R5: two-phase bucketed CSR scatter (550 -> 471).
// R6: fully bucketed CSR build + nt gather stores + degree-sorted gather order.
// R8: fix dperm contention — 100k per-thread global atomics on 64 addresses
//     (263 us, VALUBusy 0.009%) -> per-block LDS hist + range reserve (25k
//     block-level atomics), same output semantics.

static inline int cdiv(int a, int b) { return (a + b - 1) / b; }
constexpr int BLOCK = 256;
constexpr int BSHIFT = 9;                  // 512 nodes per bucket
constexpr int BNODES = 1 << BSHIFT;

typedef float nfloat4 __attribute__((ext_vector_type(4)));

// ---------------- small utils ----------------

__global__ void zero_int_kernel(int* __restrict__ p, int n) {
    int i = blockIdx.x * blockDim.x + threadIdx.x;
    if (i < n) p[i] = 0;
}

__device__ __forceinline__ void nt_store4(float* p, float4 v) {
    nfloat4 nv;
    nv.x = v.x; nv.y = v.y; nv.z = v.z; nv.w = v.w;
    __builtin_nontemporal_store(nv, (nfloat4*)p);
}

// ---------------- CSR build (fully bucketed) ----------------

// per-bucket edge counts (196 buckets), LDS-hist per chunk then global add
template <int CHUNK>
__global__ void bucket_count_kernel(const int* __restrict__ dst, int E,
                                    int* __restrict__ bcnt, int NB) {
    __shared__ int cnt[256];
    for (int i = threadIdx.x; i < NB; i += blockDim.x) cnt[i] = 0;
    __syncthreads();
    const int e0 = blockIdx.x * CHUNK;
    const int e1 = min(e0 + CHUNK, E);
    for (int e = e0 + threadIdx.x; e < e1; e += blockDim.x)
        atomicAdd(&cnt[dst[e] >> BSHIFT], 1);
    __syncthreads();
    for (int i = threadIdx.x; i < NB; i += blockDim.x)
        if (cnt[i]) atomicAdd(&bcnt[i], cnt[i]);
}

// exclusive scan of bcnt (NB<=256) -> gbase; copy to gcur (bin reservations)
__global__ void bucket_scan_kernel(const int* __restrict__ bcnt, int* __restrict__ gbase,
                                   int* __restrict__ gcur, int NB) {
    __shared__ int tmp[256];
    int t = threadIdx.x;
    int v = (t < NB) ? bcnt[t] : 0;
    tmp[t] = v;
    __syncthreads();
    for (int off = 1; off < 256; off <<= 1) {
        int add = (t >= off) ? tmp[t - off] : 0;
        __syncthreads();
        tmp[t] += add;
        __syncthreads();
    }
    if (t < NB) { int ex = tmp[t] - v; gbase[t] = ex; gcur[t] = ex; }
}

// Phase A: bin (s,d) pairs by dst bucket with contiguous-run writes
template <int CHUNK>
__global__ void bin_edges_kernel(const int* __restrict__ ei, int E,
                                 int* __restrict__ gcur, int2* __restrict__ binned,
                                 int NB) {
    __shared__ int cnt[256], base[256], rk[256];
    for (int i = threadIdx.x; i < NB; i += blockDim.x) { cnt[i] = 0; rk[i] = 0; }
    __syncthreads();
    const int e0 = blockIdx.x * CHUNK;
    const int e1 = min(e0 + CHUNK, E);
    for (int e = e0 + threadIdx.x; e < e1; e += blockDim.x)
        atomicAdd(&cnt[ei[E + e] >> BSHIFT], 1);
    __syncthreads();
    for (int i = threadIdx.x; i < NB; i += blockDim.x)
        base[i] = atomicAdd(&gcur[i], cnt[i]);
    __syncthreads();
    for (int e = e0 + threadIdx.x; e < e1; e += blockDim.x) {
        int s = ei[e], d = ei[E + e];
        int b = d >> BSHIFT;
        int r = atomicAdd(&rk[b], 1);
        binned[base[b] + r] = make_int2(s, d);
    }
}

// Phase B: one block per bucket. LDS-hist node degrees, LDS-scan to row_ptr,
// write deg/dinv/row_ptr coalesced, scatter csr_src in the L2-local window.
__global__ void csr_fill_kernel(const int* __restrict__ gbase, const int* __restrict__ bcnt,
                                const int2* __restrict__ binned,
                                int* __restrict__ deg, float* __restrict__ dinv,
                                int* __restrict__ row_ptr, int* __restrict__ csr_src, int N) {
    __shared__ int c[BNODES];    // counts, then cursors
    __shared__ int ps[256];      // pair sums for scan
    const int t = threadIdx.x;
    const int b = blockIdx.x;
    const int node0 = b << BSHIFT;
    c[t] = 0; c[t + 256] = 0;
    __syncthreads();
    const int base = gbase[b];
    const int end = base + bcnt[b];
    for (int e = base + t; e < end; e += 256)
        atomicAdd(&c[binned[e].y - node0], 1);
    __syncthreads();
    const int s0 = c[2 * t], s1 = c[2 * t + 1];
    const int pv = s0 + s1;
    ps[t] = pv;
    __syncthreads();
    for (int off = 1; off < 256; off <<= 1) {
        int add = (t >= off) ? ps[t - off] : 0;
        __syncthreads();
        ps[t] += add;
        __syncthreads();
    }
    const int ex = ps[t] - pv;          // exclusive pair offset within bucket
    const int p0 = base + ex;
    const int p1 = p0 + s0;
    const int n0 = node0 + 2 * t;
    if (n0 < N) {
        row_ptr[n0] = p0; deg[n0] = s0; dinv[n0] = rsqrtf((float)s0 + 1.0f);
        if (n0 + 1 < N) {
            row_ptr[n0 + 1] = p1; deg[n0 + 1] = s1; dinv[n0 + 1] = rsqrtf((float)s1 + 1.0f);
        }
    }
    c[2 * t] = p0; c[2 * t + 1] = p1;   // cursors
    __syncthreads();
    for (int e = base + t; e < end; e += 256) {
        int2 sd = binned[e];
        int pos = atomicAdd(&c[sd.y - node0], 1);
        csr_src[pos] = sd.x;
    }
}

// ---------------- degree counting sort (64 bins) ----------------

__global__ void dhist_kernel(const int* __restrict__ deg, int* __restrict__ dh, int N) {
    __shared__ int cnt[64];
    if (threadIdx.x < 64) cnt[threadIdx.x] = 0;
    __syncthreads();
    int i = blockIdx.x * blockDim.x + threadIdx.x;
    if (i < N) atomicAdd(&cnt[min(deg[i], 63)], 1);
    __syncthreads();
    if (threadIdx.x < 64 && cnt[threadIdx.x]) atomicAdd(&dh[threadIdx.x], cnt[threadIdx.x]);
}

// in-place: dh -> exclusive scan (becomes scatter cursors)
__global__ void dscan_kernel(int* __restrict__ dh) {
    __shared__ int tmp[64];
    int t = threadIdx.x;
    int v = dh[t];
    tmp[t] = v;
    __syncthreads();
    for (int off = 1; off < 64; off <<= 1) {
        int add = (t >= off) ? tmp[t - off] : 0;
        __syncthreads();
        tmp[t] += add;
        __syncthreads();
    }
    dh[t] = tmp[t] - v;
}

// block-aggregated permutation scatter: LDS hist -> one global reserve per
// (block,bin) -> LDS-ranked write. Avoids 100k same-address global atomics.
__global__ void dperm_kernel(const int* __restrict__ deg, int* __restrict__ dh,
                             int* __restrict__ perm, int N) {
    __shared__ int cnt[64], base[64], rk[64];
    const int t = threadIdx.x;
    if (t < 64) { cnt[t] = 0; rk[t] = 0; }
    __syncthreads();
    const int i = blockIdx.x * blockDim.x + t;
    const int myb = (i < N) ? min(deg[i], 63) : -1;
    if (myb >= 0) atomicAdd(&cnt[myb], 1);
    __syncthreads();
    if (t < 64) base[t] = cnt[t] ? atomicAdd(&dh[t], cnt[t]) : 0;
    __syncthreads();
    if (myb >= 0) {
        int r = atomicAdd(&rk[myb], 1);
        perm[base[myb] + r] = i;
    }
}

// ---------------- prescale ----------------

// xs[i,:] = x[i,:] * dinv[i]   (F=12: 3 float4 chunks per row)
__global__ void prescale_kernel(const float* __restrict__ x, const float* __restrict__ dinv,
                                float* __restrict__ xs, int N) {
    int t = blockIdx.x * blockDim.x + threadIdx.x;
    if (t >= N * 3) return;
    int i = t / 3;
    float di = dinv[i];
    float4 v = ((const float4*)x)[t];
    v.x *= di; v.y *= di; v.z *= di; v.w *= di;
    ((float4*)xs)[t] = v;
}

// ---------------- dense transform (register-tiled) ----------------

__device__ __forceinline__ void fma4(float4& acc, float s, const float4& w) {
    acc.x = fmaf(s, w.x, acc.x);
    acc.y = fmaf(s, w.y, acc.y);
    acc.z = fmaf(s, w.z, acc.z);
    acc.w = fmaf(s, w.w, acc.w);
}

template <int IN, int OUT, bool HAS_BIAS, bool RELU, bool SCALE>
__global__ void transform_kernel(const float* __restrict__ h, const float* __restrict__ W,
                                 const float* __restrict__ bias, const float* __restrict__ dinv,
                                 float* __restrict__ out, int N) {
    constexpr int CG = OUT / 4;        // col groups
    constexpr int THREADS = 8 * CG;    // 8 row groups of 4 rows
    __shared__ float Ws[IN * OUT];
    for (int i = threadIdx.x; i < IN * OUT / 4; i += THREADS)
        ((float4*)Ws)[i] = ((const float4*)W)[i];
    __syncthreads();

    const int c0 = (threadIdx.x % CG) * 4;
    const int r0 = blockIdx.x * 32 + (threadIdx.x / CG) * 4;
    if (r0 >= N) return;  // N % 32 == 0

    const float* __restrict__ hr = h + (size_t)r0 * IN;
    float4 acc[4];
#pragma unroll
    for (int i = 0; i < 4; ++i) acc[i] = make_float4(0.f, 0.f, 0.f, 0.f);

#pragma unroll
    for (int k = 0; k < IN; k += 4) {
        float4 a[4];
#pragma unroll
        for (int i = 0; i < 4; ++i) a[i] = *(const float4*)(hr + (size_t)i * IN + k);
        const float4 w0 = *(const float4*)(Ws + (k + 0) * OUT + c0);
        const float4 w1 = *(const float4*)(Ws + (k + 1) * OUT + c0);
        const float4 w2 = *(const float4*)(Ws + (k + 2) * OUT + c0);
        const float4 w3 = *(const float4*)(Ws + (k + 3) * OUT + c0);
#pragma unroll
        for (int i = 0; i < 4; ++i) {
            fma4(acc[i], a[i].x, w0);
            fma4(acc[i], a[i].y, w1);
            fma4(acc[i], a[i].z, w2);
            fma4(acc[i], a[i].w, w3);
        }
    }

    float4 bb = make_float4(0.f, 0.f, 0.f, 0.f);
    if (HAS_BIAS) bb = *(const float4*)(bias + c0);
#pragma unroll
    for (int i = 0; i < 4; ++i) {
        float4 r = acc[i];
        if (HAS_BIAS) { r.x += bb.x; r.y += bb.y; r.z += bb.z; r.w += bb.w; }
        if (RELU) {
            r.x = fmaxf(r.x, 0.f); r.y = fmaxf(r.y, 0.f);
            r.z = fmaxf(r.z, 0.f); r.w = fmaxf(r.w, 0.f);
        }
        if (SCALE) {
            float di = dinv[r0 + i];
            r.x *= di; r.y *= di; r.z *= di; r.w *= di;
        }
        *(float4*)(out + (size_t)(r0 + i) * OUT + c0) = r;
    }
}

// ---------------- pull gather ----------------

__device__ __forceinline__ void add4(float4& a, const float4& v) {
    a.x += v.x; a.y += v.y; a.z += v.z; a.w += v.w;
}

// hws rows pre-scaled by dinv[src].
// out[i, f0:f0+4] = dinv[i]*(hws[i] + sum_s hws[s]) (+ b)
// PERM: process nodes in degree-sorted order (wave-uniform loop counts).
template <int F, bool HAS_BIAS, bool PERM, bool NT>
__global__ void gather_kernel(const int* __restrict__ row_ptr, const int* __restrict__ deg,
                              const int* __restrict__ csr_src, const int* __restrict__ perm,
                              const float* __restrict__ dinv, const float* __restrict__ hws,
                              const float* __restrict__ b, float* __restrict__ out, int N) {
    constexpr int TPN = F / 4;  // threads per node
    int t = blockIdx.x * blockDim.x + threadIdx.x;
    if (t >= N * TPN) return;
    int slot = t / TPN;
    int c = t - slot * TPN;
    int i = PERM ? perm[slot] : slot;
    int f0 = c * 4;

    const int* __restrict__ sp = csr_src + row_ptr[i];
    int n = deg[i];
    float4 acc = *(const float4*)(hws + (size_t)i * F + f0);  // self loop

    int k = 0;
    for (; k + 8 <= n; k += 8) {
        int s[8];
#pragma unroll
        for (int j = 0; j < 8; ++j) s[j] = sp[k + j];
        float4 v[8];
#pragma unroll
        for (int j = 0; j < 8; ++j) v[j] = *(const float4*)(hws + (size_t)s[j] * F + f0);
#pragma unroll
        for (int j = 0; j < 8; ++j) add4(acc, v[j]);
    }
    for (; k + 4 <= n; k += 4) {
        int s0 = sp[k + 0], s1 = sp[k + 1], s2 = sp[k + 2], s3 = sp[k + 3];
        const float4 v0 = *(const float4*)(hws + (size_t)s0 * F + f0);
        const float4 v1 = *(const float4*)(hws + (size_t)s1 * F + f0);
        const float4 v2 = *(const float4*)(hws + (size_t)s2 * F + f0);
        const float4 v3 = *(const float4*)(hws + (size_t)s3 * F + f0);
        add4(acc, v0); add4(acc, v1); add4(acc, v2); add4(acc, v3);
    }
    for (; k < n; ++k) {
        const float4 v = *(const float4*)(hws + (size_t)sp[k] * F + f0);
        add4(acc, v);
    }

    float di = dinv[i];
    float4 r;
    if (HAS_BIAS) {
        const float4 bb = *(const float4*)(b + f0);
        r.x = fmaf(acc.x, di, bb.x);
        r.y = fmaf(acc.y, di, bb.y);
        r.z = fmaf(acc.z, di, bb.z);
        r.w = fmaf(acc.w, di, bb.w);
    } else {
        r.x = acc.x * di; r.y = acc.y * di; r.z = acc.z * di; r.w = acc.w * di;
    }
    float* op = out + (size_t)i * F + f0;
    if (NT) nt_store4(op, r);
    else *(float4*)op = r;
}

// ---------------- launch ----------------

extern "C" void kernel_launch(void* const* d_in, const int* in_sizes, int n_in,
                              void* d_out, int out_size, void* d_ws, size_t ws_size,
                              hipStream_t stream) {
    const float* x  = (const float*)d_in[0];
    const int*   ei = (const int*)d_in[1];  // (2,E): row0=src, row1=dst
    const float* W1 = (const float*)d_in[2];
    const float* b1 = (const float*)d_in[3];
    const float* W2 = (const float*)d_in[4];
    const float* b2 = (const float*)d_in[5];
    const float* W3 = (const float*)d_in[6];
    const float* b3 = (const float*)d_in[7];
    float* out = (float*)d_out;

    const int N = in_sizes[0] / 12;
    const int E = in_sizes[1] / 2;
    const int NB = cdiv(N, BNODES);  // 196 dst buckets (<=256)

    // workspace layout
    char* ws = (char*)d_ws;
    int*   deg     = (int*)ws;    ws += (size_t)N * sizeof(int);
    int*   row_ptr = (int*)ws;    ws += (size_t)N * sizeof(int);
    int*   perm    = (int*)ws;    ws += (size_t)N * sizeof(int);
    int*   bcnt    = (int*)ws;    ws += 256 * sizeof(int);
    int*   dh      = (int*)ws;    ws += 64 * sizeof(int);
    int*   gbase   = (int*)ws;    ws += 256 * sizeof(int);
    int*   gcur    = (int*)ws;    ws += 256 * sizeof(int);
    float* dinv    = (float*)ws;  ws += (size_t)N * sizeof(float);
    int*   csr_src = (int*)ws;    ws += (size_t)E * sizeof(int);
    float* bufA    = (float*)ws;  ws += (size_t)N * 128 * sizeof(float);  // xs / h1s / h2
    float* bufB    = (float*)ws;                                          // aggx / agg1 / hw3s
    int2*  binned  = (int2*)bufB;  // aliased: consumed by csr_fill before gathers touch bufB

    // ---- CSR build (fully bucketed; no global per-node hist/scan) ----
    zero_int_kernel<<<2, 256, 0, stream>>>(bcnt, 256 + 64);  // bcnt + dh (contiguous)
    bucket_count_kernel<4096><<<cdiv(E, 4096), BLOCK, 0, stream>>>(ei + E, E, bcnt, NB);
    bucket_scan_kernel<<<1, 256, 0, stream>>>(bcnt, gbase, gcur, NB);
    bin_edges_kernel<4096><<<cdiv(E, 4096), BLOCK, 0, stream>>>(ei, E, gcur, binned, NB);
    csr_fill_kernel<<<NB, 256, 0, stream>>>(gbase, bcnt, binned, deg, dinv, row_ptr, csr_src, N);

    // ---- degree counting sort (wave-uniform gather loops) ----
    dhist_kernel<<<cdiv(N, BLOCK), BLOCK, 0, stream>>>(deg, dh, N);
    dscan_kernel<<<1, 64, 0, stream>>>(dh);
    dperm_kernel<<<cdiv(N, BLOCK), BLOCK, 0, stream>>>(deg, dh, perm, N);

    const int tb = cdiv(N, 32);  // transform blocks

    // ---- layer 1: aggregate at F=12, then 12->64 (+b1, relu, *dinv) ----
    prescale_kernel<<<cdiv(N * 3, BLOCK), BLOCK, 0, stream>>>(x, dinv, bufA, N);
    gather_kernel<12, false, false, false><<<cdiv(N * 3, BLOCK), BLOCK, 0, stream>>>(
        row_ptr, deg, csr_src, nullptr, dinv, bufA, nullptr, bufB, N);
    transform_kernel<12, 64, true, true, true><<<tb, 8 * (64 / 4), 0, stream>>>(
        bufB, W1, b1, dinv, bufA, N);  // bufA = h1s (scaled)

    // ---- layer 2: aggregate at F=64, then 64->128 (+b2, relu) ----
    gather_kernel<64, false, true, true><<<cdiv(N * 16, BLOCK), BLOCK, 0, stream>>>(
        row_ptr, deg, csr_src, perm, dinv, bufA, nullptr, bufB, N);
    transform_kernel<64, 128, true, true, false><<<tb, 8 * (128 / 4), 0, stream>>>(
        bufB, W2, b2, dinv, bufA, N);  // bufA = h2

    // ---- layer 3: 128->96 (*dinv), then aggregate at F=96 (+b3) -> out ----
    transform_kernel<128, 96, false, false, true><<<tb, 8 * (96 / 4), 0, stream>>>(
        bufA, W3, nullptr, dinv, bufB, N);  // bufB = hw3s (scaled)
    gather_kernel<96, true, true, true><<<cdiv(N * 24, BLOCK), BLOCK, 0, stream>>>(
        row_ptr, deg, csr_src, perm, dinv, bufB, b3, out, N);
}

// Round 9
// 381.568 us; speedup vs baseline: 1.8641x; 1.1638x over previous
//
#include <hip/hip_runtime.h>
#include <hip/hip_bf16.h>
#include <hip/hip_fp16.h>

// GCN 3-layer: x(N,12) -> 64 -> 128 -> 96, symmetric normalization + self loops.
// N=100000, E=1600000.
//
// R2: CSR + pull-gather (7028 -> 1364 us).
// R3: register-tiled 4x4-microtile transform (1364 -> 693 us).
// R4: associativity reorder (aggregate at 12/64/96) + prescaled rows (693 -> 550).
// R5: two-phase bucketed CSR scatter (550 -> 471).
// R6/R8: fully bucketed CSR build, nt stores, block-aggregated degree sort (->444).
// R9: fp16 storage for the gathered feature rows (F=64/96): halves the
//     fetch-volume-bound gather traffic (gather96 FETCH 310 MB -> ~150 MB),
//     fp32 accumulation; fp16 rounding adds ~5e-4 abs err (threshold 2.7e-3).
//     Also: dhist folded into csr_fill.

static inline int cdiv(int a, int b) { return (a + b - 1) / b; }
constexpr int BLOCK = 256;
constexpr int BSHIFT = 9;                  // 512 nodes per bucket
constexpr int BNODES = 1 << BSHIFT;

typedef float nfloat4 __attribute__((ext_vector_type(4)));

// ---------------- small utils ----------------

__global__ void zero_int_kernel(int* __restrict__ p, int n) {
    int i = blockIdx.x * blockDim.x + threadIdx.x;
    if (i < n) p[i] = 0;
}

__device__ __forceinline__ void nt_store4(float* p, float4 v) {
    nfloat4 nv;
    nv.x = v.x; nv.y = v.y; nv.z = v.z; nv.w = v.w;
    __builtin_nontemporal_store(nv, (nfloat4*)p);
}

struct h4 { __half2 a, b; };  // 8 bytes = 4 fp16
__device__ __forceinline__ void store_h4(__half* p, float4 v) {
    h4 r;
    r.a = __floats2half2_rn(v.x, v.y);
    r.b = __floats2half2_rn(v.z, v.w);
    *(h4*)p = r;
}

// unpack 8 fp16 (one float4 raw load) and add into acc[0..7]
__device__ __forceinline__ void h8_add(float* acc, float4 raw) {
    union { float4 f; __half2 h[4]; } u;
    u.f = raw;
#pragma unroll
    for (int j = 0; j < 4; ++j) {
        float2 p = __half22float2(u.h[j]);
        acc[2 * j] += p.x;
        acc[2 * j + 1] += p.y;
    }
}

// ---------------- CSR build (fully bucketed) ----------------

template <int CHUNK>
__global__ void bucket_count_kernel(const int* __restrict__ dst, int E,
                                    int* __restrict__ bcnt, int NB) {
    __shared__ int cnt[256];
    for (int i = threadIdx.x; i < NB; i += blockDim.x) cnt[i] = 0;
    __syncthreads();
    const int e0 = blockIdx.x * CHUNK;
    const int e1 = min(e0 + CHUNK, E);
    for (int e = e0 + threadIdx.x; e < e1; e += blockDim.x)
        atomicAdd(&cnt[dst[e] >> BSHIFT], 1);
    __syncthreads();
    for (int i = threadIdx.x; i < NB; i += blockDim.x)
        if (cnt[i]) atomicAdd(&bcnt[i], cnt[i]);
}

__global__ void bucket_scan_kernel(const int* __restrict__ bcnt, int* __restrict__ gbase,
                                   int* __restrict__ gcur, int NB) {
    __shared__ int tmp[256];
    int t = threadIdx.x;
    int v = (t < NB) ? bcnt[t] : 0;
    tmp[t] = v;
    __syncthreads();
    for (int off = 1; off < 256; off <<= 1) {
        int add = (t >= off) ? tmp[t - off] : 0;
        __syncthreads();
        tmp[t] += add;
        __syncthreads();
    }
    if (t < NB) { int ex = tmp[t] - v; gbase[t] = ex; gcur[t] = ex; }
}

template <int CHUNK>
__global__ void bin_edges_kernel(const int* __restrict__ ei, int E,
                                 int* __restrict__ gcur, int2* __restrict__ binned,
                                 int NB) {
    __shared__ int cnt[256], base[256], rk[256];
    for (int i = threadIdx.x; i < NB; i += blockDim.x) { cnt[i] = 0; rk[i] = 0; }
    __syncthreads();
    const int e0 = blockIdx.x * CHUNK;
    const int e1 = min(e0 + CHUNK, E);
    for (int e = e0 + threadIdx.x; e < e1; e += blockDim.x)
        atomicAdd(&cnt[ei[E + e] >> BSHIFT], 1);
    __syncthreads();
    for (int i = threadIdx.x; i < NB; i += blockDim.x)
        base[i] = atomicAdd(&gcur[i], cnt[i]);
    __syncthreads();
    for (int e = e0 + threadIdx.x; e < e1; e += blockDim.x) {
        int s = ei[e], d = ei[E + e];
        int b = d >> BSHIFT;
        int r = atomicAdd(&rk[b], 1);
        binned[base[b] + r] = make_int2(s, d);
    }
}

// One block per bucket: LDS degree hist + scan -> deg/dinv/row_ptr, scatter
// csr_src in L2-local window, and fold the 64-bin degree histogram (for the
// counting sort) into the same pass.
__global__ void csr_fill_kernel(const int* __restrict__ gbase, const int* __restrict__ bcnt,
                                const int2* __restrict__ binned,
                                int* __restrict__ deg, float* __restrict__ dinv,
                                int* __restrict__ row_ptr, int* __restrict__ csr_src,
                                int* __restrict__ dh, int N) {
    __shared__ int c[BNODES];    // counts, then cursors
    __shared__ int ps[256];      // pair sums for scan
    __shared__ int dhloc[64];
    const int t = threadIdx.x;
    const int b = blockIdx.x;
    const int node0 = b << BSHIFT;
    c[t] = 0; c[t + 256] = 0;
    if (t < 64) dhloc[t] = 0;
    __syncthreads();
    const int base = gbase[b];
    const int end = base + bcnt[b];
    for (int e = base + t; e < end; e += 256)
        atomicAdd(&c[binned[e].y - node0], 1);
    __syncthreads();
    const int s0 = c[2 * t], s1 = c[2 * t + 1];
    const int pv = s0 + s1;
    ps[t] = pv;
    __syncthreads();
    for (int off = 1; off < 256; off <<= 1) {
        int add = (t >= off) ? ps[t - off] : 0;
        __syncthreads();
        ps[t] += add;
        __syncthreads();
    }
    const int ex = ps[t] - pv;
    const int p0 = base + ex;
    const int p1 = p0 + s0;
    const int n0 = node0 + 2 * t;
    if (n0 < N) {
        row_ptr[n0] = p0; deg[n0] = s0; dinv[n0] = rsqrtf((float)s0 + 1.0f);
        atomicAdd(&dhloc[min(s0, 63)], 1);
        if (n0 + 1 < N) {
            row_ptr[n0 + 1] = p1; deg[n0 + 1] = s1; dinv[n0 + 1] = rsqrtf((float)s1 + 1.0f);
            atomicAdd(&dhloc[min(s1, 63)], 1);
        }
    }
    c[2 * t] = p0; c[2 * t + 1] = p1;
    __syncthreads();
    if (t < 64 && dhloc[t]) atomicAdd(&dh[t], dhloc[t]);
    for (int e = base + t; e < end; e += 256) {
        int2 sd = binned[e];
        int pos = atomicAdd(&c[sd.y - node0], 1);
        csr_src[pos] = sd.x;
    }
}

// ---------------- degree counting sort (64 bins) ----------------

__global__ void dscan_kernel(int* __restrict__ dh) {
    __shared__ int tmp[64];
    int t = threadIdx.x;
    int v = dh[t];
    tmp[t] = v;
    __syncthreads();
    for (int off = 1; off < 64; off <<= 1) {
        int add = (t >= off) ? tmp[t - off] : 0;
        __syncthreads();
        tmp[t] += add;
        __syncthreads();
    }
    dh[t] = tmp[t] - v;
}

__global__ void dperm_kernel(const int* __restrict__ deg, int* __restrict__ dh,
                             int* __restrict__ perm, int N) {
    __shared__ int cnt[64], base[64], rk[64];
    const int t = threadIdx.x;
    if (t < 64) { cnt[t] = 0; rk[t] = 0; }
    __syncthreads();
    const int i = blockIdx.x * blockDim.x + t;
    const int myb = (i < N) ? min(deg[i], 63) : -1;
    if (myb >= 0) atomicAdd(&cnt[myb], 1);
    __syncthreads();
    if (t < 64) base[t] = cnt[t] ? atomicAdd(&dh[t], cnt[t]) : 0;
    __syncthreads();
    if (myb >= 0) {
        int r = atomicAdd(&rk[myb], 1);
        perm[base[myb] + r] = i;
    }
}

// ---------------- prescale ----------------

__global__ void prescale_kernel(const float* __restrict__ x, const float* __restrict__ dinv,
                                float* __restrict__ xs, int N) {
    int t = blockIdx.x * blockDim.x + threadIdx.x;
    if (t >= N * 3) return;
    int i = t / 3;
    float di = dinv[i];
    float4 v = ((const float4*)x)[t];
    v.x *= di; v.y *= di; v.z *= di; v.w *= di;
    ((float4*)xs)[t] = v;
}

// ---------------- dense transform (register-tiled) ----------------

__device__ __forceinline__ void fma4(float4& acc, float s, const float4& w) {
    acc.x = fmaf(s, w.x, acc.x);
    acc.y = fmaf(s, w.y, acc.y);
    acc.z = fmaf(s, w.z, acc.z);
    acc.w = fmaf(s, w.w, acc.w);
}

// out = relu?(h @ W + b) * dinv? ; OUT_HALF: store fp16 rows
template <int IN, int OUT, bool HAS_BIAS, bool RELU, bool SCALE, bool OUT_HALF>
__global__ void transform_kernel(const float* __restrict__ h, const float* __restrict__ W,
                                 const float* __restrict__ bias, const float* __restrict__ dinv,
                                 void* __restrict__ out_v, int N) {
    constexpr int CG = OUT / 4;
    constexpr int THREADS = 8 * CG;
    __shared__ float Ws[IN * OUT];
    for (int i = threadIdx.x; i < IN * OUT / 4; i += THREADS)
        ((float4*)Ws)[i] = ((const float4*)W)[i];
    __syncthreads();

    const int c0 = (threadIdx.x % CG) * 4;
    const int r0 = blockIdx.x * 32 + (threadIdx.x / CG) * 4;
    if (r0 >= N) return;  // N % 32 == 0

    const float* __restrict__ hr = h + (size_t)r0 * IN;
    float4 acc[4];
#pragma unroll
    for (int i = 0; i < 4; ++i) acc[i] = make_float4(0.f, 0.f, 0.f, 0.f);

#pragma unroll
    for (int k = 0; k < IN; k += 4) {
        float4 a[4];
#pragma unroll
        for (int i = 0; i < 4; ++i) a[i] = *(const float4*)(hr + (size_t)i * IN + k);
        const float4 w0 = *(const float4*)(Ws + (k + 0) * OUT + c0);
        const float4 w1 = *(const float4*)(Ws + (k + 1) * OUT + c0);
        const float4 w2 = *(const float4*)(Ws + (k + 2) * OUT + c0);
        const float4 w3 = *(const float4*)(Ws + (k + 3) * OUT + c0);
#pragma unroll
        for (int i = 0; i < 4; ++i) {
            fma4(acc[i], a[i].x, w0);
            fma4(acc[i], a[i].y, w1);
            fma4(acc[i], a[i].z, w2);
            fma4(acc[i], a[i].w, w3);
        }
    }

    float4 bb = make_float4(0.f, 0.f, 0.f, 0.f);
    if (HAS_BIAS) bb = *(const float4*)(bias + c0);
#pragma unroll
    for (int i = 0; i < 4; ++i) {
        float4 r = acc[i];
        if (HAS_BIAS) { r.x += bb.x; r.y += bb.y; r.z += bb.z; r.w += bb.w; }
        if (RELU) {
            r.x = fmaxf(r.x, 0.f); r.y = fmaxf(r.y, 0.f);
            r.z = fmaxf(r.z, 0.f); r.w = fmaxf(r.w, 0.f);
        }
        if (SCALE) {
            float di = dinv[r0 + i];
            r.x *= di; r.y *= di; r.z *= di; r.w *= di;
        }
        if (OUT_HALF)
            store_h4((__half*)out_v + (size_t)(r0 + i) * OUT + c0, r);
        else
            *(float4*)((float*)out_v + (size_t)(r0 + i) * OUT + c0) = r;
    }
}

// ---------------- pull gathers ----------------

__device__ __forceinline__ void add4(float4& a, const float4& v) {
    a.x += v.x; a.y += v.y; a.z += v.z; a.w += v.w;
}

// fp32 gather, F=12 (layer-1 pre-aggregation)
template <int F>
__global__ void gather_kernel(const int* __restrict__ row_ptr, const int* __restrict__ deg,
                              const int* __restrict__ csr_src,
                              const float* __restrict__ dinv, const float* __restrict__ hws,
                              float* __restrict__ out, int N) {
    constexpr int TPN = F / 4;
    int t = blockIdx.x * blockDim.x + threadIdx.x;
    if (t >= N * TPN) return;
    int i = t / TPN;
    int c = t - i * TPN;
    int f0 = c * 4;

    const int* __restrict__ sp = csr_src + row_ptr[i];
    int n = deg[i];
    float4 acc = *(const float4*)(hws + (size_t)i * F + f0);  // self loop

    int k = 0;
    for (; k + 4 <= n; k += 4) {
        int s0 = sp[k + 0], s1 = sp[k + 1], s2 = sp[k + 2], s3 = sp[k + 3];
        const float4 v0 = *(const float4*)(hws + (size_t)s0 * F + f0);
        const float4 v1 = *(const float4*)(hws + (size_t)s1 * F + f0);
        const float4 v2 = *(const float4*)(hws + (size_t)s2 * F + f0);
        const float4 v3 = *(const float4*)(hws + (size_t)s3 * F + f0);
        add4(acc, v0); add4(acc, v1); add4(acc, v2); add4(acc, v3);
    }
    for (; k < n; ++k) {
        const float4 v = *(const float4*)(hws + (size_t)sp[k] * F + f0);
        add4(acc, v);
    }

    float di = dinv[i];
    float4 r;
    r.x = acc.x * di; r.y = acc.y * di; r.z = acc.z * di; r.w = acc.w * di;
    *(float4*)(out + (size_t)i * F + f0) = r;
}

// fp16-input gather: each thread covers 8 features (16 B/edge), fp32 accum.
// Degree-sorted (perm) order; nontemporal fp32 output.
template <int F, bool HAS_BIAS>
__global__ void gather_h_kernel(const int* __restrict__ row_ptr, const int* __restrict__ deg,
                                const int* __restrict__ csr_src, const int* __restrict__ perm,
                                const float* __restrict__ dinv, const __half* __restrict__ hws,
                                const float* __restrict__ b, float* __restrict__ out, int N) {
    constexpr int TPN = F / 8;
    int t = blockIdx.x * blockDim.x + threadIdx.x;
    if (t >= N * TPN) return;
    int slot = t / TPN;
    int c = t - slot * TPN;
    int i = perm[slot];
    int f0 = c * 8;

    const int* __restrict__ sp = csr_src + row_ptr[i];
    int n = deg[i];
    float acc[8];
    {
        union { float4 f; __half2 h[4]; } u;
        u.f = *(const float4*)(hws + (size_t)i * F + f0);  // self loop
#pragma unroll
        for (int j = 0; j < 4; ++j) {
            float2 p = __half22float2(u.h[j]);
            acc[2 * j] = p.x; acc[2 * j + 1] = p.y;
        }
    }

    int k = 0;
    for (; k + 4 <= n; k += 4) {
        int s0 = sp[k + 0], s1 = sp[k + 1], s2 = sp[k + 2], s3 = sp[k + 3];
        float4 v0 = *(const float4*)(hws + (size_t)s0 * F + f0);
        float4 v1 = *(const float4*)(hws + (size_t)s1 * F + f0);
        float4 v2 = *(const float4*)(hws + (size_t)s2 * F + f0);
        float4 v3 = *(const float4*)(hws + (size_t)s3 * F + f0);
        h8_add(acc, v0); h8_add(acc, v1); h8_add(acc, v2); h8_add(acc, v3);
    }
    for (; k < n; ++k) {
        float4 v = *(const float4*)(hws + (size_t)sp[k] * F + f0);
        h8_add(acc, v);
    }

    float di = dinv[i];
    float4 r0, r1;
    if (HAS_BIAS) {
        const float4 bb0 = *(const float4*)(b + f0);
        const float4 bb1 = *(const float4*)(b + f0 + 4);
        r0.x = fmaf(acc[0], di, bb0.x); r0.y = fmaf(acc[1], di, bb0.y);
        r0.z = fmaf(acc[2], di, bb0.z); r0.w = fmaf(acc[3], di, bb0.w);
        r1.x = fmaf(acc[4], di, bb1.x); r1.y = fmaf(acc[5], di, bb1.y);
        r1.z = fmaf(acc[6], di, bb1.z); r1.w = fmaf(acc[7], di, bb1.w);
    } else {
        r0.x = acc[0] * di; r0.y = acc[1] * di; r0.z = acc[2] * di; r0.w = acc[3] * di;
        r1.x = acc[4] * di; r1.y = acc[5] * di; r1.z = acc[6] * di; r1.w = acc[7] * di;
    }
    float* op = out + (size_t)i * F + f0;
    nt_store4(op, r0);
    nt_store4(op + 4, r1);
}

// ---------------- launch ----------------

extern "C" void kernel_launch(void* const* d_in, const int* in_sizes, int n_in,
                              void* d_out, int out_size, void* d_ws, size_t ws_size,
                              hipStream_t stream) {
    const float* x  = (const float*)d_in[0];
    const int*   ei = (const int*)d_in[1];  // (2,E): row0=src, row1=dst
    const float* W1 = (const float*)d_in[2];
    const float* b1 = (const float*)d_in[3];
    const float* W2 = (const float*)d_in[4];
    const float* b2 = (const float*)d_in[5];
    const float* W3 = (const float*)d_in[6];
    const float* b3 = (const float*)d_in[7];
    float* out = (float*)d_out;

    const int N = in_sizes[0] / 12;
    const int E = in_sizes[1] / 2;
    const int NB = cdiv(N, BNODES);  // 196 dst buckets (<=256)

    // workspace layout
    char* ws = (char*)d_ws;
    int*   deg     = (int*)ws;    ws += (size_t)N * sizeof(int);
    int*   row_ptr = (int*)ws;    ws += (size_t)N * sizeof(int);
    int*   perm    = (int*)ws;    ws += (size_t)N * sizeof(int);
    int*   bcnt    = (int*)ws;    ws += 256 * sizeof(int);
    int*   dh      = (int*)ws;    ws += 64 * sizeof(int);
    int*   gbase   = (int*)ws;    ws += 256 * sizeof(int);
    int*   gcur    = (int*)ws;    ws += 256 * sizeof(int);
    float* dinv    = (float*)ws;  ws += (size_t)N * sizeof(float);
    int*   csr_src = (int*)ws;    ws += (size_t)E * sizeof(int);
    float* bufA    = (float*)ws;  ws += (size_t)N * 128 * sizeof(float);  // xs / h1h / h2
    float* bufB    = (float*)ws;                                          // aggx / agg1 / hw3h
    int2*  binned  = (int2*)bufB;  // aliased: consumed by csr_fill before gathers touch bufB

    // ---- CSR build (fully bucketed) ----
    zero_int_kernel<<<2, 256, 0, stream>>>(bcnt, 256 + 64);  // bcnt + dh (contiguous)
    bucket_count_kernel<4096><<<cdiv(E, 4096), BLOCK, 0, stream>>>(ei + E, E, bcnt, NB);
    bucket_scan_kernel<<<1, 256, 0, stream>>>(bcnt, gbase, gcur, NB);
    bin_edges_kernel<4096><<<cdiv(E, 4096), BLOCK, 0, stream>>>(ei, E, gcur, binned, NB);
    csr_fill_kernel<<<NB, 256, 0, stream>>>(gbase, bcnt, binned, deg, dinv, row_ptr,
                                            csr_src, dh, N);

    // ---- degree counting sort ----
    dscan_kernel<<<1, 64, 0, stream>>>(dh);
    dperm_kernel<<<cdiv(N, BLOCK), BLOCK, 0, stream>>>(deg, dh, perm, N);

    const int tb = cdiv(N, 32);  // transform blocks

    // ---- layer 1: aggregate at F=12 (fp32), then 12->64 (+b1, relu, *dinv, ->fp16) ----
    prescale_kernel<<<cdiv(N * 3, BLOCK), BLOCK, 0, stream>>>(x, dinv, bufA, N);
    gather_kernel<12><<<cdiv(N * 3, BLOCK), BLOCK, 0, stream>>>(
        row_ptr, deg, csr_src, dinv, bufA, bufB, N);
    transform_kernel<12, 64, true, true, true, true><<<tb, 8 * (64 / 4), 0, stream>>>(
        bufB, W1, b1, dinv, bufA, N);  // bufA = h1h (fp16, scaled)

    // ---- layer 2: aggregate at F=64 (fp16 in), then 64->128 (+b2, relu) ----
    gather_h_kernel<64, false><<<cdiv(N * 8, BLOCK), BLOCK, 0, stream>>>(
        row_ptr, deg, csr_src, perm, dinv, (const __half*)bufA, nullptr, bufB, N);
    transform_kernel<64, 128, true, true, false, false><<<tb, 8 * (128 / 4), 0, stream>>>(
        bufB, W2, b2, dinv, bufA, N);  // bufA = h2 (fp32)

    // ---- layer 3: 128->96 (*dinv, ->fp16), then aggregate at F=96 (+b3) -> out ----
    transform_kernel<128, 96, false, false, true, true><<<tb, 8 * (96 / 4), 0, stream>>>(
        bufA, W3, nullptr, dinv, bufB, N);  // bufB = hw3h (fp16, scaled)
    gather_h_kernel<96, true><<<cdiv(N * 12, BLOCK), BLOCK, 0, stream>>>(
        row_ptr, deg, csr_src, perm, dinv, (const __half*)bufB, b3, out, N);
}

// Round 10
// 351.914 us; speedup vs baseline: 2.0212x; 1.0843x over previous
//
#include <hip/hip_runtime.h>
#include <hip/hip_bf16.h>
#include <hip/hip_fp16.h>

// GCN 3-layer: x(N,12) -> 64 -> 128 -> 96, symmetric normalization + self loops.
// N=100000, E=1600000.
//
// R2: CSR + pull-gather (7028 -> 1364 us).           R3: 4x4-tile transform (-> 693).
// R4: aggregate at min-width 12/64/96, prescale (-> 550).
// R5/R6/R8: bucketed CSR build, nt stores, degree sort (-> 444).
// R9: fp16 feature rows for gathers (-> 382).
// R10: (a) v_dot2_f32_f16 transforms for layers 2/3 (fp16 x fp16 -> fp32 acc):
//      halves big-GEMM VALU work + halves agg1/h2 streams.
//      (b) binned edge pairs packed into one int (s:17b | dst_local:9b).

static inline int cdiv(int a, int b) { return (a + b - 1) / b; }
constexpr int BLOCK = 256;
constexpr int BSHIFT = 9;                  // 512 nodes per bucket
constexpr int BNODES = 1 << BSHIFT;

typedef float nfloat4 __attribute__((ext_vector_type(4)));
typedef _Float16 hh2 __attribute__((ext_vector_type(2)));

#if __has_builtin(__builtin_amdgcn_fdot2)
__device__ __forceinline__ float FDOT2(hh2 a, hh2 b, float c) {
    return __builtin_amdgcn_fdot2(a, b, c, false);
}
#else
__device__ __forceinline__ float FDOT2(hh2 a, hh2 b, float c) {
    return c + (float)a.x * (float)b.x + (float)a.y * (float)b.y;
}
#endif

// ---------------- small utils ----------------

__global__ void zero_int_kernel(int* __restrict__ p, int n) {
    int i = blockIdx.x * blockDim.x + threadIdx.x;
    if (i < n) p[i] = 0;
}

__device__ __forceinline__ void nt_store_raw16(void* p, float4 v) {
    nfloat4 nv;
    nv.x = v.x; nv.y = v.y; nv.z = v.z; nv.w = v.w;
    __builtin_nontemporal_store(nv, (nfloat4*)p);
}

struct h4 { __half2 a, b; };  // 8 bytes = 4 fp16
__device__ __forceinline__ void store_h4(__half* p, float4 v) {
    h4 r;
    r.a = __floats2half2_rn(v.x, v.y);
    r.b = __floats2half2_rn(v.z, v.w);
    *(h4*)p = r;
}

// unpack 8 fp16 (one float4 raw load) and add into acc[0..7]
__device__ __forceinline__ void h8_add(float* acc, float4 raw) {
    union { float4 f; __half2 h[4]; } u;
    u.f = raw;
#pragma unroll
    for (int j = 0; j < 4; ++j) {
        float2 p = __half22float2(u.h[j]);
        acc[2 * j] += p.x;
        acc[2 * j + 1] += p.y;
    }
}

// ---------------- CSR build (fully bucketed) ----------------

template <int CHUNK>
__global__ void bucket_count_kernel(const int* __restrict__ dst, int E,
                                    int* __restrict__ bcnt, int NB) {
    __shared__ int cnt[256];
    for (int i = threadIdx.x; i < NB; i += blockDim.x) cnt[i] = 0;
    __syncthreads();
    const int e0 = blockIdx.x * CHUNK;
    const int e1 = min(e0 + CHUNK, E);
    for (int e = e0 + threadIdx.x; e < e1; e += blockDim.x)
        atomicAdd(&cnt[dst[e] >> BSHIFT], 1);
    __syncthreads();
    for (int i = threadIdx.x; i < NB; i += blockDim.x)
        if (cnt[i]) atomicAdd(&bcnt[i], cnt[i]);
}

__global__ void bucket_scan_kernel(const int* __restrict__ bcnt, int* __restrict__ gbase,
                                   int* __restrict__ gcur, int NB) {
    __shared__ int tmp[256];
    int t = threadIdx.x;
    int v = (t < NB) ? bcnt[t] : 0;
    tmp[t] = v;
    __syncthreads();
    for (int off = 1; off < 256; off <<= 1) {
        int add = (t >= off) ? tmp[t - off] : 0;
        __syncthreads();
        tmp[t] += add;
        __syncthreads();
    }
    if (t < NB) { int ex = tmp[t] - v; gbase[t] = ex; gcur[t] = ex; }
}

// Phase A: bin edges by dst bucket; entry packed as s | (dst_local << 17)
template <int CHUNK>
__global__ void bin_edges_kernel(const int* __restrict__ ei, int E,
                                 int* __restrict__ gcur, unsigned* __restrict__ binned,
                                 int NB) {
    __shared__ int cnt[256], base[256], rk[256];
    for (int i = threadIdx.x; i < NB; i += blockDim.x) { cnt[i] = 0; rk[i] = 0; }
    __syncthreads();
    const int e0 = blockIdx.x * CHUNK;
    const int e1 = min(e0 + CHUNK, E);
    for (int e = e0 + threadIdx.x; e < e1; e += blockDim.x)
        atomicAdd(&cnt[ei[E + e] >> BSHIFT], 1);
    __syncthreads();
    for (int i = threadIdx.x; i < NB; i += blockDim.x)
        base[i] = atomicAdd(&gcur[i], cnt[i]);
    __syncthreads();
    for (int e = e0 + threadIdx.x; e < e1; e += blockDim.x) {
        int s = ei[e], d = ei[E + e];
        int b = d >> BSHIFT;
        int r = atomicAdd(&rk[b], 1);
        binned[base[b] + r] = (unsigned)s | ((unsigned)(d & (BNODES - 1)) << 17);
    }
}

// Phase B: one block per bucket. LDS degree hist + scan -> deg/dinv/row_ptr,
// scatter csr_src in L2-local window; 64-bin degree hist folded in.
__global__ void csr_fill_kernel(const int* __restrict__ gbase, const int* __restrict__ bcnt,
                                const unsigned* __restrict__ binned,
                                int* __restrict__ deg, float* __restrict__ dinv,
                                int* __restrict__ row_ptr, int* __restrict__ csr_src,
                                int* __restrict__ dh, int N) {
    __shared__ int c[BNODES];    // counts, then cursors
    __shared__ int ps[256];      // pair sums for scan
    __shared__ int dhloc[64];
    const int t = threadIdx.x;
    const int b = blockIdx.x;
    const int node0 = b << BSHIFT;
    c[t] = 0; c[t + 256] = 0;
    if (t < 64) dhloc[t] = 0;
    __syncthreads();
    const int base = gbase[b];
    const int end = base + bcnt[b];
    for (int e = base + t; e < end; e += 256)
        atomicAdd(&c[binned[e] >> 17], 1);
    __syncthreads();
    const int s0 = c[2 * t], s1 = c[2 * t + 1];
    const int pv = s0 + s1;
    ps[t] = pv;
    __syncthreads();
    for (int off = 1; off < 256; off <<= 1) {
        int add = (t >= off) ? ps[t - off] : 0;
        __syncthreads();
        ps[t] += add;
        __syncthreads();
    }
    const int ex = ps[t] - pv;
    const int p0 = base + ex;
    const int p1 = p0 + s0;
    const int n0 = node0 + 2 * t;
    if (n0 < N) {
        row_ptr[n0] = p0; deg[n0] = s0; dinv[n0] = rsqrtf((float)s0 + 1.0f);
        atomicAdd(&dhloc[min(s0, 63)], 1);
        if (n0 + 1 < N) {
            row_ptr[n0 + 1] = p1; deg[n0 + 1] = s1; dinv[n0 + 1] = rsqrtf((float)s1 + 1.0f);
            atomicAdd(&dhloc[min(s1, 63)], 1);
        }
    }
    c[2 * t] = p0; c[2 * t + 1] = p1;
    __syncthreads();
    if (t < 64 && dhloc[t]) atomicAdd(&dh[t], dhloc[t]);
    for (int e = base + t; e < end; e += 256) {
        unsigned sd = binned[e];
        int pos = atomicAdd(&c[sd >> 17], 1);
        csr_src[pos] = (int)(sd & 0x1FFFFu);
    }
}

// ---------------- degree counting sort (64 bins) ----------------

__global__ void dscan_kernel(int* __restrict__ dh) {
    __shared__ int tmp[64];
    int t = threadIdx.x;
    int v = dh[t];
    tmp[t] = v;
    __syncthreads();
    for (int off = 1; off < 64; off <<= 1) {
        int add = (t >= off) ? tmp[t - off] : 0;
        __syncthreads();
        tmp[t] += add;
        __syncthreads();
    }
    dh[t] = tmp[t] - v;
}

__global__ void dperm_kernel(const int* __restrict__ deg, int* __restrict__ dh,
                             int* __restrict__ perm, int N) {
    __shared__ int cnt[64], base[64], rk[64];
    const int t = threadIdx.x;
    if (t < 64) { cnt[t] = 0; rk[t] = 0; }
    __syncthreads();
    const int i = blockIdx.x * blockDim.x + t;
    const int myb = (i < N) ? min(deg[i], 63) : -1;
    if (myb >= 0) atomicAdd(&cnt[myb], 1);
    __syncthreads();
    if (t < 64) base[t] = cnt[t] ? atomicAdd(&dh[t], cnt[t]) : 0;
    __syncthreads();
    if (myb >= 0) {
        int r = atomicAdd(&rk[myb], 1);
        perm[base[myb] + r] = i;
    }
}

// ---------------- prescale ----------------

__global__ void prescale_kernel(const float* __restrict__ x, const float* __restrict__ dinv,
                                float* __restrict__ xs, int N) {
    int t = blockIdx.x * blockDim.x + threadIdx.x;
    if (t >= N * 3) return;
    int i = t / 3;
    float di = dinv[i];
    float4 v = ((const float4*)x)[t];
    v.x *= di; v.y *= di; v.z *= di; v.w *= di;
    ((float4*)xs)[t] = v;
}

// ---------------- dense transforms ----------------

__device__ __forceinline__ void fma4(float4& acc, float s, const float4& w) {
    acc.x = fmaf(s, w.x, acc.x);
    acc.y = fmaf(s, w.y, acc.y);
    acc.z = fmaf(s, w.z, acc.z);
    acc.w = fmaf(s, w.w, acc.w);
}

__device__ __forceinline__ float4 epilogue4(float4 r, const float* bias, int c0,
                                            bool has_bias, bool relu, bool scale, float di) {
    if (has_bias) {
        const float4 bb = *(const float4*)(bias + c0);
        r.x += bb.x; r.y += bb.y; r.z += bb.z; r.w += bb.w;
    }
    if (relu) {
        r.x = fmaxf(r.x, 0.f); r.y = fmaxf(r.y, 0.f);
        r.z = fmaxf(r.z, 0.f); r.w = fmaxf(r.w, 0.f);
    }
    if (scale) { r.x *= di; r.y *= di; r.z *= di; r.w *= di; }
    return r;
}

// fp32-input transform (layer 1: 12 -> 64), fp16 output rows
template <int IN, int OUT, bool HAS_BIAS, bool RELU, bool SCALE, bool OUT_HALF>
__global__ void transform_kernel(const float* __restrict__ h, const float* __restrict__ W,
                                 const float* __restrict__ bias, const float* __restrict__ dinv,
                                 void* __restrict__ out_v, int N) {
    constexpr int CG = OUT / 4;
    constexpr int THREADS = 8 * CG;
    __shared__ float Ws[IN * OUT];
    for (int i = threadIdx.x; i < IN * OUT / 4; i += THREADS)
        ((float4*)Ws)[i] = ((const float4*)W)[i];
    __syncthreads();

    const int c0 = (threadIdx.x % CG) * 4;
    const int r0 = blockIdx.x * 32 + (threadIdx.x / CG) * 4;
    if (r0 >= N) return;  // N % 32 == 0

    const float* __restrict__ hr = h + (size_t)r0 * IN;
    float4 acc[4];
#pragma unroll
    for (int i = 0; i < 4; ++i) acc[i] = make_float4(0.f, 0.f, 0.f, 0.f);

#pragma unroll
    for (int k = 0; k < IN; k += 4) {
        float4 a[4];
#pragma unroll
        for (int i = 0; i < 4; ++i) a[i] = *(const float4*)(hr + (size_t)i * IN + k);
        const float4 w0 = *(const float4*)(Ws + (k + 0) * OUT + c0);
        const float4 w1 = *(const float4*)(Ws + (k + 1) * OUT + c0);
        const float4 w2 = *(const float4*)(Ws + (k + 2) * OUT + c0);
        const float4 w3 = *(const float4*)(Ws + (k + 3) * OUT + c0);
#pragma unroll
        for (int i = 0; i < 4; ++i) {
            fma4(acc[i], a[i].x, w0);
            fma4(acc[i], a[i].y, w1);
            fma4(acc[i], a[i].z, w2);
            fma4(acc[i], a[i].w, w3);
        }
    }

#pragma unroll
    for (int i = 0; i < 4; ++i) {
        float di = SCALE ? dinv[r0 + i] : 0.f;
        float4 r = epilogue4(acc[i], bias, c0, HAS_BIAS, RELU, SCALE, di);
        if (OUT_HALF)
            store_h4((__half*)out_v + (size_t)(r0 + i) * OUT + c0, r);
        else
            *(float4*)((float*)out_v + (size_t)(r0 + i) * OUT + c0) = r;
    }
}

// fp16-input transform (layers 2,3) using v_dot2_f32_f16; fp32 accumulation.
// LDS holds W as fp16 K-pairs: Ws[k2*OUT + col] = {W[2k2][col], W[2k2+1][col]}
template <int IN, int OUT, bool HAS_BIAS, bool RELU, bool SCALE, bool OUT_HALF>
__global__ void transform_h_kernel(const __half* __restrict__ h, const float* __restrict__ W,
                                   const float* __restrict__ bias, const float* __restrict__ dinv,
                                   void* __restrict__ out_v, int N) {
    constexpr int CG = OUT / 4;
    constexpr int THREADS = 8 * CG;
    __shared__ hh2 Ws[(IN / 2) * OUT];
    for (int i = threadIdx.x; i < (IN / 2) * OUT; i += THREADS) {
        int k2 = i / OUT, col = i - k2 * OUT;
        hh2 w;
        w.x = (_Float16)W[(2 * k2) * OUT + col];
        w.y = (_Float16)W[(2 * k2 + 1) * OUT + col];
        Ws[i] = w;
    }
    __syncthreads();

    const int c0 = (threadIdx.x % CG) * 4;
    const int r0 = blockIdx.x * 32 + (threadIdx.x / CG) * 4;
    if (r0 >= N) return;

    const __half* __restrict__ hr = h + (size_t)r0 * IN;
    float4 acc[4];
#pragma unroll
    for (int i = 0; i < 4; ++i) acc[i] = make_float4(0.f, 0.f, 0.f, 0.f);

#pragma unroll
    for (int k = 0; k < IN; k += 8) {  // 8 halves (16 B) per row per step
        union { float4 f; hh2 p[4]; } a[4];
#pragma unroll
        for (int r = 0; r < 4; ++r) a[r].f = *(const float4*)(hr + (size_t)r * IN + k);
#pragma unroll
        for (int j = 0; j < 4; ++j) {
            union { float4 f; hh2 p[4]; } w;
            w.f = *(const float4*)(Ws + ((k / 2 + j) * OUT + c0));
#pragma unroll
            for (int r = 0; r < 4; ++r) {
                acc[r].x = FDOT2(a[r].p[j], w.p[0], acc[r].x);
                acc[r].y = FDOT2(a[r].p[j], w.p[1], acc[r].y);
                acc[r].z = FDOT2(a[r].p[j], w.p[2], acc[r].z);
                acc[r].w = FDOT2(a[r].p[j], w.p[3], acc[r].w);
            }
        }
    }

#pragma unroll
    for (int i = 0; i < 4; ++i) {
        float di = SCALE ? dinv[r0 + i] : 0.f;
        float4 r = epilogue4(acc[i], bias, c0, HAS_BIAS, RELU, SCALE, di);
        if (OUT_HALF)
            store_h4((__half*)out_v + (size_t)(r0 + i) * OUT + c0, r);
        else
            *(float4*)((float*)out_v + (size_t)(r0 + i) * OUT + c0) = r;
    }
}

// ---------------- pull gathers ----------------

__device__ __forceinline__ void add4(float4& a, const float4& v) {
    a.x += v.x; a.y += v.y; a.z += v.z; a.w += v.w;
}

// fp32 gather, F=12 (layer-1 pre-aggregation)
template <int F>
__global__ void gather_kernel(const int* __restrict__ row_ptr, const int* __restrict__ deg,
                              const int* __restrict__ csr_src,
                              const float* __restrict__ dinv, const float* __restrict__ hws,
                              float* __restrict__ out, int N) {
    constexpr int TPN = F / 4;
    int t = blockIdx.x * blockDim.x + threadIdx.x;
    if (t >= N * TPN) return;
    int i = t / TPN;
    int c = t - i * TPN;
    int f0 = c * 4;

    const int* __restrict__ sp = csr_src + row_ptr[i];
    int n = deg[i];
    float4 acc = *(const float4*)(hws + (size_t)i * F + f0);  // self loop

    int k = 0;
    for (; k + 4 <= n; k += 4) {
        int s0 = sp[k + 0], s1 = sp[k + 1], s2 = sp[k + 2], s3 = sp[k + 3];
        const float4 v0 = *(const float4*)(hws + (size_t)s0 * F + f0);
        const float4 v1 = *(const float4*)(hws + (size_t)s1 * F + f0);
        const float4 v2 = *(const float4*)(hws + (size_t)s2 * F + f0);
        const float4 v3 = *(const float4*)(hws + (size_t)s3 * F + f0);
        add4(acc, v0); add4(acc, v1); add4(acc, v2); add4(acc, v3);
    }
    for (; k < n; ++k) {
        const float4 v = *(const float4*)(hws + (size_t)sp[k] * F + f0);
        add4(acc, v);
    }

    float di = dinv[i];
    float4 r;
    r.x = acc.x * di; r.y = acc.y * di; r.z = acc.z * di; r.w = acc.w * di;
    *(float4*)(out + (size_t)i * F + f0) = r;
}

// fp16-input gather: 8 features/thread (16 B/edge), fp32 accum, degree-sorted.
// OUT_HALF: fp16 output rows (for the next fp16 transform); else fp32 + bias.
template <int F, bool HAS_BIAS, bool OUT_HALF>
__global__ void gather_h_kernel(const int* __restrict__ row_ptr, const int* __restrict__ deg,
                                const int* __restrict__ csr_src, const int* __restrict__ perm,
                                const float* __restrict__ dinv, const __half* __restrict__ hws,
                                const float* __restrict__ b, void* __restrict__ out_v, int N) {
    constexpr int TPN = F / 8;
    int t = blockIdx.x * blockDim.x + threadIdx.x;
    if (t >= N * TPN) return;
    int slot = t / TPN;
    int c = t - slot * TPN;
    int i = perm[slot];
    int f0 = c * 8;

    const int* __restrict__ sp = csr_src + row_ptr[i];
    int n = deg[i];
    float acc[8];
    {
        union { float4 f; __half2 h[4]; } u;
        u.f = *(const float4*)(hws + (size_t)i * F + f0);  // self loop
#pragma unroll
        for (int j = 0; j < 4; ++j) {
            float2 p = __half22float2(u.h[j]);
            acc[2 * j] = p.x; acc[2 * j + 1] = p.y;
        }
    }

    int k = 0;
    for (; k + 4 <= n; k += 4) {
        int s0 = sp[k + 0], s1 = sp[k + 1], s2 = sp[k + 2], s3 = sp[k + 3];
        float4 v0 = *(const float4*)(hws + (size_t)s0 * F + f0);
        float4 v1 = *(const float4*)(hws + (size_t)s1 * F + f0);
        float4 v2 = *(const float4*)(hws + (size_t)s2 * F + f0);
        float4 v3 = *(const float4*)(hws + (size_t)s3 * F + f0);
        h8_add(acc, v0); h8_add(acc, v1); h8_add(acc, v2); h8_add(acc, v3);
    }
    for (; k < n; ++k) {
        float4 v = *(const float4*)(hws + (size_t)sp[k] * F + f0);
        h8_add(acc, v);
    }

    float di = dinv[i];
    float4 r0, r1;
    if (HAS_BIAS) {
        const float4 bb0 = *(const float4*)(b + f0);
        const float4 bb1 = *(const float4*)(b + f0 + 4);
        r0.x = fmaf(acc[0], di, bb0.x); r0.y = fmaf(acc[1], di, bb0.y);
        r0.z = fmaf(acc[2], di, bb0.z); r0.w = fmaf(acc[3], di, bb0.w);
        r1.x = fmaf(acc[4], di, bb1.x); r1.y = fmaf(acc[5], di, bb1.y);
        r1.z = fmaf(acc[6], di, bb1.z); r1.w = fmaf(acc[7], di, bb1.w);
    } else {
        r0.x = acc[0] * di; r0.y = acc[1] * di; r0.z = acc[2] * di; r0.w = acc[3] * di;
        r1.x = acc[4] * di; r1.y = acc[5] * di; r1.z = acc[6] * di; r1.w = acc[7] * di;
    }
    if (OUT_HALF) {
        union { float4 f; __half2 h[4]; } u;
        u.h[0] = __floats2half2_rn(r0.x, r0.y);
        u.h[1] = __floats2half2_rn(r0.z, r0.w);
        u.h[2] = __floats2half2_rn(r1.x, r1.y);
        u.h[3] = __floats2half2_rn(r1.z, r1.w);
        nt_store_raw16((__half*)out_v + (size_t)i * F + f0, u.f);
    } else {
        float* op = (float*)out_v + (size_t)i * F + f0;
        nt_store_raw16(op, r0);
        nt_store_raw16(op + 4, r1);
    }
}

// ---------------- launch ----------------

extern "C" void kernel_launch(void* const* d_in, const int* in_sizes, int n_in,
                              void* d_out, int out_size, void* d_ws, size_t ws_size,
                              hipStream_t stream) {
    const float* x  = (const float*)d_in[0];
    const int*   ei = (const int*)d_in[1];  // (2,E): row0=src, row1=dst
    const float* W1 = (const float*)d_in[2];
    const float* b1 = (const float*)d_in[3];
    const float* W2 = (const float*)d_in[4];
    const float* b2 = (const float*)d_in[5];
    const float* W3 = (const float*)d_in[6];
    const float* b3 = (const float*)d_in[7];
    float* out = (float*)d_out;

    const int N = in_sizes[0] / 12;
    const int E = in_sizes[1] / 2;
    const int NB = cdiv(N, BNODES);  // 196 dst buckets (<=256)

    // workspace layout
    char* ws = (char*)d_ws;
    int*   deg     = (int*)ws;    ws += (size_t)N * sizeof(int);
    int*   row_ptr = (int*)ws;    ws += (size_t)N * sizeof(int);
    int*   perm    = (int*)ws;    ws += (size_t)N * sizeof(int);
    int*   bcnt    = (int*)ws;    ws += 256 * sizeof(int);
    int*   dh      = (int*)ws;    ws += 64 * sizeof(int);
    int*   gbase   = (int*)ws;    ws += 256 * sizeof(int);
    int*   gcur    = (int*)ws;    ws += 256 * sizeof(int);
    float* dinv    = (float*)ws;  ws += (size_t)N * sizeof(float);
    int*   csr_src = (int*)ws;    ws += (size_t)E * sizeof(int);
    float* bufA    = (float*)ws;  ws += (size_t)N * 128 * sizeof(float);  // xs / h1h / h2h
    float* bufB    = (float*)ws;                                          // aggx / agg1h / hw3h
    unsigned* binned = (unsigned*)bufB;  // aliased: consumed before bufB reused

    // ---- CSR build (fully bucketed) ----
    zero_int_kernel<<<2, 256, 0, stream>>>(bcnt, 256 + 64);  // bcnt + dh (contiguous)
    bucket_count_kernel<4096><<<cdiv(E, 4096), BLOCK, 0, stream>>>(ei + E, E, bcnt, NB);
    bucket_scan_kernel<<<1, 256, 0, stream>>>(bcnt, gbase, gcur, NB);
    bin_edges_kernel<4096><<<cdiv(E, 4096), BLOCK, 0, stream>>>(ei, E, gcur, binned, NB);
    csr_fill_kernel<<<NB, 256, 0, stream>>>(gbase, bcnt, binned, deg, dinv, row_ptr,
                                            csr_src, dh, N);

    // ---- degree counting sort ----
    dscan_kernel<<<1, 64, 0, stream>>>(dh);
    dperm_kernel<<<cdiv(N, BLOCK), BLOCK, 0, stream>>>(deg, dh, perm, N);

    const int tb = cdiv(N, 32);  // transform blocks

    // ---- layer 1: aggregate at F=12 (fp32), then 12->64 (+b1, relu, *dinv, ->fp16) ----
    prescale_kernel<<<cdiv(N * 3, BLOCK), BLOCK, 0, stream>>>(x, dinv, bufA, N);
    gather_kernel<12><<<cdiv(N * 3, BLOCK), BLOCK, 0, stream>>>(
        row_ptr, deg, csr_src, dinv, bufA, bufB, N);
    transform_kernel<12, 64, true, true, true, true><<<tb, 8 * (64 / 4), 0, stream>>>(
        bufB, W1, b1, dinv, bufA, N);  // bufA = h1h (fp16, scaled)

    // ---- layer 2: aggregate at F=64 (fp16->fp16), then 64->128 fdot2 (+b2, relu, ->fp16) ----
    gather_h_kernel<64, false, true><<<cdiv(N * 8, BLOCK), BLOCK, 0, stream>>>(
        row_ptr, deg, csr_src, perm, dinv, (const __half*)bufA, nullptr, bufB, N);
    transform_h_kernel<64, 128, true, true, false, true><<<tb, 8 * (128 / 4), 0, stream>>>(
        (const __half*)bufB, W2, b2, dinv, bufA, N);  // bufA = h2h (fp16)

    // ---- layer 3: 128->96 fdot2 (*dinv, ->fp16), then aggregate at F=96 (+b3) -> out ----
    transform_h_kernel<128, 96, false, false, true, true><<<tb, 8 * (96 / 4), 0, stream>>>(
        (const __half*)bufA, W3, nullptr, dinv, bufB, N);  // bufB = hw3h (fp16, scaled)
    gather_h_kernel<96, true, false><<<cdiv(N * 12, BLOCK), BLOCK, 0, stream>>>(
        row_ptr, deg, csr_src, perm, dinv, (const __half*)bufB, b3, out, N);
}